// Round 1
// baseline (139.561 us; speedup 1.0000x reference)
//
#include <hip/hip_runtime.h>

#define BB 2
#define NN 768
#define FF 128
#define HH 128
#define TS 32
#define ROWS 8

// k0: pack score-MLP weights as doubles: wpack[c] = {w1[0,c], w1[1,c], b1[c], w2[c,1]-w2[c,0]}
__global__ void pack_weights_kernel(const float* __restrict__ sm_w1,
                                    const float* __restrict__ sm_b1,
                                    const float* __restrict__ sm_w2,
                                    double* __restrict__ wpack) {
    int c = threadIdx.x;
    if (c < HH) {
        wpack[4 * c + 0] = (double)sm_w1[c];
        wpack[4 * c + 1] = (double)sm_w1[HH + c];
        wpack[4 * c + 2] = (double)sm_b1[c];
        wpack[4 * c + 3] = (double)sm_w2[2 * c + 1] - (double)sm_w2[2 * c + 0];
    }
}

// k1: feats = relu(X@w1+b1)@w2+b2  (f64 accum); Xc[b,k,i,d] = X[b,i,2d+k] + gate*feats[2d+k]
__global__ __launch_bounds__(128)
void edgefeat_kernel(const float* __restrict__ X,
                     const float* __restrict__ w1, const float* __restrict__ b1,
                     const float* __restrict__ w2, const float* __restrict__ b2,
                     const float* __restrict__ gatep,
                     double* __restrict__ Xc) {
    __shared__ float  Xs[ROWS][FF];
    __shared__ double Hs[ROWS][HH];
    const int h = threadIdx.x;            // 0..127 output column
    const int row0 = blockIdx.x * ROWS;   // global row in [0, B*N)
    for (int r = 0; r < ROWS; ++r) Xs[r][h] = X[(size_t)(row0 + r) * FF + h];
    __syncthreads();
    double acc[ROWS];
    double bb = (double)b1[h];
    for (int r = 0; r < ROWS; ++r) acc[r] = bb;
    for (int f = 0; f < FF; ++f) {
        double w = (double)w1[f * HH + h];        // coalesced across h
        for (int r = 0; r < ROWS; ++r) acc[r] = fma((double)Xs[r][f], w, acc[r]);
    }
    for (int r = 0; r < ROWS; ++r) Hs[r][h] = acc[r] > 0.0 ? acc[r] : 0.0;
    __syncthreads();
    bb = (double)b2[h];
    for (int r = 0; r < ROWS; ++r) acc[r] = bb;
    for (int c = 0; c < HH; ++c) {
        double w = (double)w2[c * HH + h];
        for (int r = 0; r < ROWS; ++r) acc[r] = fma(Hs[r][c], w, acc[r]);
    }
    const double gate = (double)gatep[0];
    const int k = h & 1, d = h >> 1;
    const int b = row0 / NN;
    const int i0 = row0 % NN;
    for (int r = 0; r < ROWS; ++r) {
        double v = (double)Xs[r][h] + gate * acc[r];
        Xc[(((size_t)(b * 2 + k)) * NN + (i0 + r)) * 64 + d] = v;
    }
}

// k2: per 32x32 tile (ti<=tj): gram (D=64, f64) -> edge MLP (H=128, f64) -> gumbel argmax -> symmetric write
__global__ __launch_bounds__(256, 2)
void edge_decide_kernel(const double* __restrict__ Xc,
                        const double* __restrict__ wpack,
                        const float* __restrict__ sm_b2,
                        const float* __restrict__ gumbel,
                        float* __restrict__ out) {
    const int ti = blockIdx.x, tj = blockIdx.y, b = blockIdx.z;
    if (tj < ti) return;
    __shared__ double Ai[2][TS][66];   // pad 66: breaks pow2 bank stride, keeps 16B align
    __shared__ double Aj[2][TS][66];
    __shared__ float  As[TS][TS + 1];
    const int tid = threadIdx.x;
    const int i0 = ti * TS, j0 = tj * TS;

    // stage Xc tiles (coalesced double2 global reads)
    for (int q = 0; q < 8; ++q) {
        int flat = tid + 256 * q;           // pair index 0..2047
        int k  = flat >> 10;
        int r  = (flat >> 5) & 31;
        int dp = flat & 31;
        size_t base = ((size_t)(b * 2 + k)) * NN;
        double2 vi = *(const double2*)&Xc[(base + i0 + r) * 64 + 2 * dp];
        *(double2*)&Ai[k][r][2 * dp] = vi;
        double2 vj = *(const double2*)&Xc[(base + j0 + r) * 64 + 2 * dp];
        *(double2*)&Aj[k][r][2 * dp] = vj;
    }
    __syncthreads();

    const int rh = tid >> 4;         // 0..15
    const int ch = tid & 15;         // 0..15
    const int r0 = rh, r1 = rh + 16;
    const int c0 = 2 * ch, c1 = c0 + 1;

    // gram: p[k][re][ce]
    double p000 = 0, p001 = 0, p010 = 0, p011 = 0;
    double p100 = 0, p101 = 0, p110 = 0, p111 = 0;
    for (int d2 = 0; d2 < 32; ++d2) {
        double2 a00 = *(const double2*)&Ai[0][r0][2 * d2];
        double2 a01 = *(const double2*)&Ai[0][r1][2 * d2];
        double2 a10 = *(const double2*)&Ai[1][r0][2 * d2];
        double2 a11 = *(const double2*)&Ai[1][r1][2 * d2];
        double2 b00 = *(const double2*)&Aj[0][c0][2 * d2];
        double2 b01 = *(const double2*)&Aj[0][c1][2 * d2];
        double2 b10 = *(const double2*)&Aj[1][c0][2 * d2];
        double2 b11 = *(const double2*)&Aj[1][c1][2 * d2];
        p000 = fma(a00.y, b00.y, fma(a00.x, b00.x, p000));
        p001 = fma(a00.y, b01.y, fma(a00.x, b01.x, p001));
        p010 = fma(a01.y, b00.y, fma(a01.x, b00.x, p010));
        p011 = fma(a01.y, b01.y, fma(a01.x, b01.x, p011));
        p100 = fma(a10.y, b10.y, fma(a10.x, b10.x, p100));
        p101 = fma(a10.y, b11.y, fma(a10.x, b11.x, p101));
        p110 = fma(a11.y, b10.y, fma(a11.x, b10.x, p110));
        p111 = fma(a11.y, b11.y, fma(a11.x, b11.x, p111));
    }

    // margin init: (b2[1]-b2[0]) + (g1-g0) per edge; gumbel only matters at upper (i,j)
    const double bd = (double)sm_b2[1] - (double)sm_b2[0];
    float4 g0v = *(const float4*)&gumbel[(((size_t)b * NN + i0 + r0) * NN + j0 + c0) * 2];
    float4 g1v = *(const float4*)&gumbel[(((size_t)b * NN + i0 + r1) * NN + j0 + c0) * 2];
    double m00 = bd + ((double)g0v.y - (double)g0v.x);
    double m01 = bd + ((double)g0v.w - (double)g0v.z);
    double m10 = bd + ((double)g1v.y - (double)g1v.x);
    double m11 = bd + ((double)g1v.w - (double)g1v.z);

    // edge MLP: m += sum_c wd_c * relu(p0*a_c + p1*b_c + beta_c)   (weights via uniform/scalar loads)
    for (int c = 0; c < HH; ++c) {
        double2 wab = *(const double2*)&wpack[4 * c];        // a, b
        double2 wbw = *(const double2*)&wpack[4 * c + 2];    // beta, wd
        double t;
        t = fma(p100, wab.y, fma(p000, wab.x, wbw.x)); t = fmax(t, 0.0); m00 = fma(t, wbw.y, m00);
        t = fma(p101, wab.y, fma(p001, wab.x, wbw.x)); t = fmax(t, 0.0); m01 = fma(t, wbw.y, m01);
        t = fma(p110, wab.y, fma(p010, wab.x, wbw.x)); t = fmax(t, 0.0); m10 = fma(t, wbw.y, m10);
        t = fma(p111, wab.y, fma(p011, wab.x, wbw.x)); t = fmax(t, 0.0); m11 = fma(t, wbw.y, m11);
    }

    float A00 = m00 > 0.0 ? 1.0f : 0.0f;
    float A01 = m01 > 0.0 ? 1.0f : 0.0f;
    float A10 = m10 > 0.0 ? 1.0f : 0.0f;
    float A11 = m11 > 0.0 ? 1.0f : 0.0f;

    As[r0][c0] = A00; As[r0][c1] = A01;
    As[r1][c0] = A10; As[r1][c1] = A11;
    __syncthreads();

    if (ti != tj) {
        // direct tile (i<j guaranteed)
        *(float2*)&out[((size_t)b * NN + i0 + r0) * NN + j0 + c0] = make_float2(A00, A01);
        *(float2*)&out[((size_t)b * NN + i0 + r1) * NN + j0 + c0] = make_float2(A10, A11);
        // transposed tile: out[b, j0+jr, i0+ic] = As[ic][jr]
        float2 t0 = make_float2(As[c0][r0], As[c1][r0]);
        *(float2*)&out[((size_t)b * NN + j0 + r0) * NN + i0 + c0] = t0;
        float2 t1 = make_float2(As[c0][r1], As[c1][r1]);
        *(float2*)&out[((size_t)b * NN + j0 + r1) * NN + i0 + c0] = t1;
    } else {
        // diagonal tile: upper value mirrored, diag = 0
        float v00 = (r0 < c0) ? As[r0][c0] : ((r0 > c0) ? As[c0][r0] : 0.0f);
        float v01 = (r0 < c1) ? As[r0][c1] : ((r0 > c1) ? As[c1][r0] : 0.0f);
        float v10 = (r1 < c0) ? As[r1][c0] : ((r1 > c0) ? As[c0][r1] : 0.0f);
        float v11 = (r1 < c1) ? As[r1][c1] : ((r1 > c1) ? As[c1][r1] : 0.0f);
        *(float2*)&out[((size_t)b * NN + i0 + r0) * NN + j0 + c0] = make_float2(v00, v01);
        *(float2*)&out[((size_t)b * NN + i0 + r1) * NN + j0 + c0] = make_float2(v10, v11);
    }
}

extern "C" void kernel_launch(void* const* d_in, const int* in_sizes, int n_in,
                              void* d_out, int out_size, void* d_ws, size_t ws_size,
                              hipStream_t stream) {
    const float* X      = (const float*)d_in[0];
    const float* ef_w1  = (const float*)d_in[1];
    const float* ef_b1  = (const float*)d_in[2];
    const float* ef_w2  = (const float*)d_in[3];
    const float* ef_b2  = (const float*)d_in[4];
    const float* gate   = (const float*)d_in[5];
    const float* sm_w1  = (const float*)d_in[6];
    const float* sm_b1  = (const float*)d_in[7];
    const float* sm_w2  = (const float*)d_in[8];
    const float* sm_b2  = (const float*)d_in[9];
    const float* gumbel = (const float*)d_in[10];
    float* out = (float*)d_out;

    double* Xc    = (double*)d_ws;                       // B*2*N*64 doubles = 1.5 MiB
    double* wpack = Xc + (size_t)BB * 2 * NN * 64;       // 512 doubles

    pack_weights_kernel<<<1, 128, 0, stream>>>(sm_w1, sm_b1, sm_w2, wpack);
    edgefeat_kernel<<<BB * NN / ROWS, 128, 0, stream>>>(X, ef_w1, ef_b1, ef_w2, ef_b2, gate, Xc);
    dim3 grid(NN / TS, NN / TS, BB);
    edge_decide_kernel<<<grid, 256, 0, stream>>>(Xc, wpack, sm_b2, gumbel, out);
}